// Round 6
// baseline (1310.907 us; speedup 1.0000x reference)
//
#include <hip/hip_runtime.h>
#include <hip/hip_bf16.h>
#include <cstdint>
#include <cstddef>

#define MAX_K 70
#define LCAP 128
#define BN_EPS 1e-5f

typedef __attribute__((ext_vector_type(4))) float f32x4;
typedef __attribute__((ext_vector_type(8))) short bf16x8;

// ---------------- load/store helpers (f32 or bf16 storage) ----------------
__device__ inline float loadv(const float* p, size_t i) { return p[i]; }
__device__ inline float loadv(const __hip_bfloat16* p, size_t i) {
    return __bfloat162float(p[i]);
}
__device__ inline void storev(float* p, size_t i, float v) { p[i] = v; }
__device__ inline void storev(__hip_bfloat16* p, size_t i, float v) {
    p[i] = __float2bfloat16(v);
}
__device__ inline float bf2f(unsigned short u) {
    union { unsigned int i; float f; } x; x.i = ((unsigned int)u) << 16; return x.f;
}
__device__ inline unsigned short f2bfu(float f) {
    __hip_bfloat16 h = __float2bfloat16(f);
    return *reinterpret_cast<unsigned short*>(&h);
}

// ---------------------------------------------------------------- utilities
__global__ void zero_kernel(float* __restrict__ p, size_t n) {
    size_t i = (size_t)blockIdx.x * blockDim.x + threadIdx.x;
    size_t stride = (size_t)gridDim.x * blockDim.x;
    for (; i < n; i += stride) p[i] = 0.f;
}

// ------------------------------------------------------ stage 1a: histogram
__global__ void hist_kernel(const int4* __restrict__ cc4,
                            int* __restrict__ cnt, int n4) {
    int i = blockIdx.x * blockDim.x + threadIdx.x;
    int stride = gridDim.x * blockDim.x;
    for (int q = i; q < n4; q += stride) {
        int4 v = cc4[q];
        atomicAdd(&cnt[v.x], 1);
        atomicAdd(&cnt[v.y], 1);
        atomicAdd(&cnt[v.z], 1);
        atomicAdd(&cnt[v.w], 1);
    }
}

// --------------------------------------- stage 1b: exclusive scan over cnt
__global__ __launch_bounds__(256) void scan_partial(const int* __restrict__ cnt,
                                                    int* __restrict__ bsum, int C) {
    __shared__ int sc[256];
    int b = blockIdx.x, tid = threadIdx.x;
    int base = b * 2048 + tid * 8;
    int t = 0;
    #pragma unroll
    for (int e = 0; e < 8; ++e) {
        int c = base + e;
        t += (c < C) ? cnt[c] : 0;
    }
    sc[tid] = t;
    __syncthreads();
    for (int o = 128; o > 0; o >>= 1) {
        if (tid < o) sc[tid] += sc[tid + o];
        __syncthreads();
    }
    if (tid == 0) bsum[b] = sc[0];
}

__global__ void scan_tops(int* __restrict__ bsum, int nb) {
    if (blockIdx.x == 0 && threadIdx.x == 0) {
        int run = 0;
        for (int k = 0; k < nb; ++k) { int t = bsum[k]; bsum[k] = run; run += t; }
    }
}

__global__ __launch_bounds__(256) void scan_final(const int* __restrict__ cnt,
                                                  const int* __restrict__ btop,
                                                  int* __restrict__ off,
                                                  int* __restrict__ woff, int C) {
    __shared__ int sc[256];
    int b = blockIdx.x, tid = threadIdx.x;
    int base = b * 2048 + tid * 8;
    int v[8];
    int tsum = 0;
    #pragma unroll
    for (int e = 0; e < 8; ++e) {
        int c = base + e;
        v[e] = (c < C) ? cnt[c] : 0;
        tsum += v[e];
    }
    sc[tid] = tsum;
    __syncthreads();
    for (int d = 1; d < 256; d <<= 1) {
        int t = (tid >= d) ? sc[tid - d] : 0;
        __syncthreads();
        sc[tid] += t;
        __syncthreads();
    }
    int run = btop[b] + sc[tid] - tsum;
    #pragma unroll
    for (int e = 0; e < 8; ++e) {
        int c = base + e;
        if (c < C) { off[c] = run; woff[c] = run; }
        run += v[e];
    }
}

// --------- stage 1c: inverse permutation. Reads linear, writes COALESCED.
__global__ __launch_bounds__(256) void scatter_inv_kernel(
    const int4* __restrict__ cc4, int* __restrict__ woff,
    int4* __restrict__ inv4, int n4) {
    int i = blockIdx.x * 256 + threadIdx.x;
    int stride = gridDim.x * 256;
    for (int q = i; q < n4; q += stride) {
        int4 c = cc4[q];
        int4 p;
        p.x = atomicAdd(&woff[c.x], 1);
        p.y = atomicAdd(&woff[c.y], 1);
        p.z = atomicAdd(&woff[c.z], 1);
        p.w = atomicAdd(&woff[c.w], 1);
        inv4[q] = p;
    }
}

// --------- stage 1d: payload-carrying reorder, XCD-partitioned by p-range.
// Each group (XCD) scans inv+feat LINEARLY (L3-resident after first touch)
// and writes only its contiguous slice of sorted/sortedFeat (confined lines).
__global__ __launch_bounds__(256) void gather8_kernel(
    const int* __restrict__ inv, const float* __restrict__ feat,
    int* __restrict__ sorted, float* __restrict__ sfeat, int N, int pcg) {
    int g   = blockIdx.x & 7;
    int plo = g * pcg;
    int phi = min(plo + pcg, N);
    int i0     = (blockIdx.x >> 3) * 256 + threadIdx.x;
    int stride = (gridDim.x >> 3) * 256;
    for (int i = i0; i < N; i += stride) {
        int p = inv[i];
        if (p >= plo && p < phi) {
            sorted[p] = i;
            size_t fb = (size_t)i * 5, sb = (size_t)p * 5;
            float a0 = feat[fb + 0], a1 = feat[fb + 1], a2 = feat[fb + 2];
            float a3 = feat[fb + 3], a4 = feat[fb + 4];
            sfeat[sb + 0] = a0; sfeat[sb + 1] = a1; sfeat[sb + 2] = a2;
            sfeat[sb + 3] = a3; sfeat[sb + 4] = a4;
        }
    }
}

// ------------- stage 1e+2a: rank, pack (coalesced), layer-1 GEMM (350->32)
// one wave per component, 4 components per block
__global__ __launch_bounds__(256) void layer1_kernel(
    const float* __restrict__ sfeat, const int* __restrict__ cnt,
    const int* __restrict__ off, const int* __restrict__ sorted,
    const float* __restrict__ W1, const float* __restrict__ b1,
    float* __restrict__ z1, int C) {
    __shared__ int   sidx[4][LCAP];
    __shared__ short srank[4][LCAP];
    __shared__ float xtile[4][MAX_K * 5];
    int w    = threadIdx.x >> 6;
    int lane = threadIdx.x & 63;
    int comp = blockIdx.x * 4 + w;
    int flen = 0, base = 0;
    if (comp < C) { flen = cnt[comp]; base = off[comp]; }
    bool small = (flen <= LCAP);
    int len = min(flen, LCAP);
    if (small) {
        for (int e = lane; e < len; e += 64) sidx[w][e] = sorted[base + e];
    }
    __syncthreads();
    if (small) {
        // deterministic rank = number of member indices smaller than mine
        for (int e = lane; e < len; e += 64) {
            int my = sidx[w][e];
            int r = 0;
            for (int j = 0; j < len; ++j) r += (sidx[w][j] < my) ? 1 : 0;
            srank[w][e] = (short)r;
        }
    }
    __syncthreads();
    if (small) {
        // pack: global reads are CONTIGUOUS (lane t reads word base*5+t)
        int tot = len * 5;
        for (int t = lane; t < tot; t += 64) {
            int m = t / 5;
            int k = t - m * 5;
            float v = sfeat[(size_t)base * 5 + t];
            int r = srank[w][m];
            if (r < MAX_K) xtile[w][r * 5 + k] = v;
        }
    } else if (comp < C) {
        // never taken for this data; correctness fallback via global reads
        for (int e = lane; e < flen; e += 64) {
            int my = sorted[base + e];
            int r = 0;
            for (int j = 0; j < flen; ++j) r += (sorted[base + j] < my) ? 1 : 0;
            if (r < MAX_K) {
                #pragma unroll
                for (int k = 0; k < 5; ++k)
                    xtile[w][r * 5 + k] = sfeat[(size_t)(base + e) * 5 + k];
            }
        }
    }
    __syncthreads();
    // GEMM: split K across two 32-lane halves, combine via shfl
    int ch = lane & 31;
    int h  = lane >> 5;
    int kmax = min(flen, MAX_K) * 5;
    float acc = 0.f;
    for (int t = h; t < kmax; t += 2)
        acc = fmaf(xtile[w][t], W1[t * 32 + ch], acc);
    float tot = acc + __shfl_xor(acc, 32);
    if (comp < C && lane < 32)
        z1[(size_t)comp * 32 + lane] = tot + b1[lane];
}

// --------------------------------------- per-channel sum / sumsq reduction
template <typename T, int FO>
__global__ __launch_bounds__(256) void reduce_kernel(
    const T* __restrict__ z, double* __restrict__ dsum,
    double* __restrict__ dsq, int C) {
    size_t n = (size_t)C * FO;
    size_t i = (size_t)blockIdx.x * 256 + threadIdx.x;
    size_t stride = (size_t)gridDim.x * 256;
    double s = 0.0, s2 = 0.0;
    for (; i < n; i += stride) {
        double v = (double)loadv(z, i);
        s += v; s2 += v * v;
    }
    __shared__ double ss[256], ssq[256];
    int tid = threadIdx.x;
    ss[tid] = s; ssq[tid] = s2;
    __syncthreads();
    for (int off = (256 / FO) >> 1; off > 0; off >>= 1) {
        if (tid < off * FO) {
            ss[tid]  += ss[tid + off * FO];
            ssq[tid] += ssq[tid + off * FO];
        }
        __syncthreads();
    }
    if (tid < FO) {
        unsafeAtomicAdd(&dsum[tid], ss[tid]);
        unsafeAtomicAdd(&dsq[tid],  ssq[tid]);
    }
}

// ------------------------------- fold BN stats into per-channel scale/shift
template <int FO>
__global__ void finalize_kernel(const double* __restrict__ dsum,
                                const double* __restrict__ dsq,
                                const float* __restrict__ g,
                                const float* __restrict__ be,
                                float* __restrict__ aS, float* __restrict__ cS,
                                int C) {
    int ch = threadIdx.x;
    if (ch < FO) {
        double m = dsum[ch] / (double)C;
        double v = dsq[ch] / (double)C - m * m;
        float rs = rsqrtf((float)v + BN_EPS);
        float a = g[ch] * rs;
        aS[ch] = a;
        cS[ch] = be[ch] - (float)m * a;
    }
}

// ---- generic layer: zout = relu(aS*zin+cS) @ W + b, with fused BN stats ----
template <typename TI, typename TO, int FI, int FO, int CT, int RT>
__global__ __launch_bounds__(256) void layer_kernel(
    const TI* __restrict__ zin, const float* __restrict__ W,
    const float* __restrict__ bias, const float* __restrict__ aS,
    const float* __restrict__ cS, TO* __restrict__ zout,
    double* __restrict__ dsum, double* __restrict__ dsq, int C) {
    constexpr int CHG  = FO / CT;
    constexpr int NSUB = 256 / CHG;
    constexpr int R    = NSUB * RT;
    __shared__ float h[R][FI + 1];
    __shared__ float sps[NSUB * FO];
    __shared__ float spq[NSUB * FO];
    int tid = threadIdx.x;
    int c0 = blockIdx.x * R;
    for (int t = tid; t < R * FI; t += 256) {
        int r = t / FI, k = t % FI;
        int c = c0 + r;
        float v = (c < C) ? loadv(zin, (size_t)c * FI + k) : 0.f;
        h[r][k] = fmaxf(fmaf(aS[k], v, cS[k]), 0.f);
    }
    __syncthreads();
    int cg  = tid % CHG;
    int sub = tid / CHG;
    int chbase = cg * CT;
    float acc[RT][CT];
    #pragma unroll
    for (int i = 0; i < RT; ++i)
        #pragma unroll
        for (int j = 0; j < CT; ++j) acc[i][j] = 0.f;
    for (int k = 0; k < FI; ++k) {
        float wv[CT];
        #pragma unroll
        for (int j4 = 0; j4 < CT; j4 += 4) {
            const float4 wq = *reinterpret_cast<const float4*>(
                &W[(size_t)k * FO + chbase + j4]);
            wv[j4 + 0] = wq.x; wv[j4 + 1] = wq.y;
            wv[j4 + 2] = wq.z; wv[j4 + 3] = wq.w;
        }
        #pragma unroll
        for (int i = 0; i < RT; ++i) {
            float hv = h[sub * RT + i][k];
            #pragma unroll
            for (int j = 0; j < CT; ++j) acc[i][j] = fmaf(hv, wv[j], acc[i][j]);
        }
    }
    float ps[CT], pq[CT];
    #pragma unroll
    for (int j = 0; j < CT; ++j) { ps[j] = 0.f; pq[j] = 0.f; }
    #pragma unroll
    for (int i = 0; i < RT; ++i) {
        int c = c0 + sub * RT + i;
        if (c < C) {
            #pragma unroll
            for (int j = 0; j < CT; ++j) {
                float z = acc[i][j] + bias[chbase + j];
                storev(zout, (size_t)c * FO + chbase + j, z);
                ps[j] += z;
                pq[j] += z * z;
            }
        }
    }
    #pragma unroll
    for (int j = 0; j < CT; ++j) {
        sps[sub * FO + chbase + j] = ps[j];
        spq[sub * FO + chbase + j] = pq[j];
    }
    __syncthreads();
    if (tid < FO) {
        float s = 0.f, q = 0.f;
        #pragma unroll
        for (int s2 = 0; s2 < NSUB; ++s2) {
            s += sps[s2 * FO + tid];
            q += spq[s2 * FO + tid];
        }
        unsafeAtomicAdd(&dsum[tid], (double)s);
        unsafeAtomicAdd(&dsq[tid],  (double)q);
    }
}

// ---------------- W4 f32[128][256] -> bf16 transposed w4t[256][128] --------
__global__ void w4conv_kernel(const float* __restrict__ W4,
                              unsigned short* __restrict__ w4t) {
    int idx = blockIdx.x * 256 + threadIdx.x;  // 32768 total
    int n = idx >> 7, k = idx & 127;
    w4t[idx] = f2bfu(W4[k * 256 + n]);
}

// ------------- layer 4 via MFMA: z4 = relu(bn3(z3)) @ W4 + b4, fused stats
__global__ __launch_bounds__(256) void layer4_mfma(
    const __hip_bfloat16* __restrict__ z3, const unsigned short* __restrict__ w4t,
    const float* __restrict__ b4, const float* __restrict__ aS,
    const float* __restrict__ cS, __hip_bfloat16* __restrict__ z4,
    double* __restrict__ dsum, double* __restrict__ dsq, int C) {
    __shared__ float sps[2][256];
    __shared__ float spq[2][256];
    int tid = threadIdx.x, wid = tid >> 6, lane = tid & 63;
    int wm = wid >> 1, wn = wid & 1;
    int c0 = blockIdx.x * 64;
    int l15 = lane & 15, l4 = lane >> 4;
    const unsigned short* z3u = (const unsigned short*)z3;

    f32x4 acc[2][8];
    #pragma unroll
    for (int mi = 0; mi < 2; ++mi)
        #pragma unroll
        for (int ni = 0; ni < 8; ++ni) acc[mi][ni] = (f32x4){0.f, 0.f, 0.f, 0.f};

    int rowA0 = c0 + wm * 32 + l15;
    #pragma unroll
    for (int ks = 0; ks < 4; ++ks) {
        int k0 = ks * 32 + l4 * 8;
        float sc[8], cc[8];
        {
            float4 a0 = *(const float4*)&aS[k0];
            float4 a1 = *(const float4*)&aS[k0 + 4];
            float4 c0v = *(const float4*)&cS[k0];
            float4 c1v = *(const float4*)&cS[k0 + 4];
            sc[0] = a0.x; sc[1] = a0.y; sc[2] = a0.z; sc[3] = a0.w;
            sc[4] = a1.x; sc[5] = a1.y; sc[6] = a1.z; sc[7] = a1.w;
            cc[0] = c0v.x; cc[1] = c0v.y; cc[2] = c0v.z; cc[3] = c0v.w;
            cc[4] = c1v.x; cc[5] = c1v.y; cc[6] = c1v.z; cc[7] = c1v.w;
        }
        bf16x8 afrag[2];
        #pragma unroll
        for (int mi = 0; mi < 2; ++mi) {
            int r = rowA0 + mi * 16;
            int rc = (r < C) ? r : (C - 1);
            bf16x8 raw = *(const bf16x8*)&z3u[(size_t)rc * 128 + k0];
            bf16x8 af;
            #pragma unroll
            for (int j = 0; j < 8; ++j) {
                float v = bf2f((unsigned short)raw[j]);
                float hx = fmaxf(fmaf(sc[j], v, cc[j]), 0.f);
                af[j] = (short)f2bfu((r < C) ? hx : 0.f);
            }
            afrag[mi] = af;
        }
        bf16x8 bfrag[8];
        #pragma unroll
        for (int ni = 0; ni < 8; ++ni) {
            int n = wn * 128 + ni * 16 + l15;
            bfrag[ni] = *(const bf16x8*)&w4t[(size_t)n * 128 + k0];
        }
        #pragma unroll
        for (int mi = 0; mi < 2; ++mi)
            #pragma unroll
            for (int ni = 0; ni < 8; ++ni)
                acc[mi][ni] = __builtin_amdgcn_mfma_f32_16x16x32_bf16(
                    afrag[mi], bfrag[ni], acc[mi][ni], 0, 0, 0);
    }
    unsigned short* z4u = (unsigned short*)z4;
    #pragma unroll
    for (int ni = 0; ni < 8; ++ni) {
        int col = wn * 128 + ni * 16 + l15;
        float bv = b4[col];
        float s = 0.f, q = 0.f;
        #pragma unroll
        for (int mi = 0; mi < 2; ++mi) {
            #pragma unroll
            for (int r = 0; r < 4; ++r) {
                int row = c0 + wm * 32 + mi * 16 + l4 * 4 + r;
                float z = acc[mi][ni][r] + bv;
                if (row < C) {
                    z4u[(size_t)row * 256 + col] = f2bfu(z);
                    s += z;
                    q += z * z;
                }
            }
        }
        s += __shfl_xor(s, 16); s += __shfl_xor(s, 32);
        q += __shfl_xor(q, 16); q += __shfl_xor(q, 32);
        if (lane < 16) { sps[wm][col] = s; spq[wm][col] = q; }
    }
    __syncthreads();
    if (tid < 256) {
        float s = sps[0][tid] + sps[1][tid];
        float q = spq[0][tid] + spq[1][tid];
        unsafeAtomicAdd(&dsum[tid], (double)s);
        unsafeAtomicAdd(&dsq[tid],  (double)q);
    }
}

// ----------------------------------------------- per-image component counts
__global__ void imgcnt_kernel(const int* __restrict__ imgid,
                              int* __restrict__ pcnt, int C, int B) {
    __shared__ int scnt[64];
    int tid = threadIdx.x;
    if (tid < B) scnt[tid] = 0;
    __syncthreads();
    for (int i = blockIdx.x * 256 + tid; i < C; i += gridDim.x * 256)
        atomicAdd(&scnt[imgid[i]], 1);
    __syncthreads();
    if (tid < B) atomicAdd(&pcnt[tid], scnt[tid]);
}

// ------------- segment-sum of relu(bn4(z4)) into pool[B,256] (LDS accum)
__global__ __launch_bounds__(256) void pool_kernel(
    const __hip_bfloat16* __restrict__ z4, const int* __restrict__ imgid,
    const float* __restrict__ aS, const float* __restrict__ cS,
    float* __restrict__ pool, int C, int B) {
    __shared__ float spool[64 * 256];
    int tid = threadIdx.x;
    int nb = B * 256;
    for (int t = tid; t < nb; t += 256) spool[t] = 0.f;
    __syncthreads();
    float a = aS[tid], cc = cS[tid];
    int per  = (C + gridDim.x - 1) / gridDim.x;
    int cbeg = blockIdx.x * per;
    int cend = min(cbeg + per, C);
    for (int c = cbeg; c < cend; ++c) {
        int img = imgid[c];
        float v = loadv(z4, (size_t)c * 256 + tid);
        float hv = fmaxf(fmaf(a, v, cc), 0.f);
        spool[img * 256 + tid] += hv;
    }
    __syncthreads();
    int start = ((int)blockIdx.x * 2048) % nb;
    for (int t0 = 0; t0 < nb; t0 += 256) {
        int t = (start + t0 + tid) % nb;
        unsafeAtomicAdd(&pool[t], spool[t]);
    }
}

// ------------------------------ mean over comps, BN over the 64 image rows
__global__ void bn5_kernel(const float* __restrict__ pool,
                           const int* __restrict__ pcnt,
                           const float* __restrict__ g5,
                           const float* __restrict__ be5,
                           float* __restrict__ y, int B) {
    int ch = threadIdx.x;
    double s = 0.0, s2 = 0.0;
    for (int b = 0; b < B; ++b) {
        float c = (float)pcnt[b]; if (c < 1.f) c = 1.f;
        float v = pool[b * 256 + ch] / c;
        s += (double)v; s2 += (double)v * (double)v;
    }
    double m = s / (double)B;
    double var = s2 / (double)B - m * m;
    float rs = rsqrtf((float)var + BN_EPS);
    float a = g5[ch] * rs;
    float cc = be5[ch] - (float)m * a;
    for (int b = 0; b < B; ++b) {
        float c = (float)pcnt[b]; if (c < 1.f) c = 1.f;
        float v = pool[b * 256 + ch] / c;
        y[b * 256 + ch] = fmaf(a, v, cc);
    }
}

// ------------------------------------------------------- final FC + ReLU
__global__ __launch_bounds__(256) void fc_kernel(
    const float* __restrict__ y, const float* __restrict__ Wfc,
    const float* __restrict__ bfc, float* __restrict__ out, int NC) {
    int b = blockIdx.y;
    int ch = blockIdx.x * 256 + threadIdx.x;
    __shared__ float sy[256];
    sy[threadIdx.x] = y[b * 256 + threadIdx.x];
    __syncthreads();
    if (ch < NC) {
        float acc = bfc[ch];
        for (int k = 0; k < 256; ++k)
            acc = fmaf(sy[k], Wfc[(size_t)k * NC + ch], acc);
        out[(size_t)b * NC + ch] = fmaxf(acc, 0.f);
    }
}

// ---------------------------------------------------------------- launcher
extern "C" void kernel_launch(void* const* d_in, const int* in_sizes, int n_in,
                              void* d_out, int out_size, void* d_ws,
                              size_t ws_size, hipStream_t stream) {
    const float* item_feat = (const float*)d_in[0];
    const int*   ccids     = (const int*)d_in[1];
    const int*   imgid     = (const int*)d_in[2];
    const float* W1  = (const float*)d_in[3];
    const float* b1  = (const float*)d_in[4];
    const float* g1  = (const float*)d_in[5];
    const float* be1 = (const float*)d_in[6];
    const float* W2  = (const float*)d_in[7];
    const float* b2  = (const float*)d_in[8];
    const float* g2  = (const float*)d_in[9];
    const float* be2 = (const float*)d_in[10];
    const float* W3  = (const float*)d_in[11];
    const float* b3  = (const float*)d_in[12];
    const float* g3  = (const float*)d_in[13];
    const float* be3 = (const float*)d_in[14];
    const float* W4  = (const float*)d_in[15];
    const float* b4  = (const float*)d_in[16];
    const float* g4  = (const float*)d_in[17];
    const float* be4 = (const float*)d_in[18];
    const float* g5  = (const float*)d_in[19];
    const float* be5 = (const float*)d_in[20];
    const float* Wfc = (const float*)d_in[21];
    const float* bfc = (const float*)d_in[22];
    float* out = (float*)d_out;

    const int N  = in_sizes[1];        // 4,000,000 items
    const int C  = in_sizes[2];        // 200,000 components
    const int NC = in_sizes[22];       // 1000 classes
    const int B  = out_size / NC;      // 64 images

    // ---- workspace layout: explicit liveness-based aliasing ----
    uint8_t* ws = (uint8_t*)d_ws;
    size_t off_ = 0;
    auto alloc = [&](size_t bytes) -> void* {
        void* p = (void*)(ws + off_);
        off_ += (bytes + 255) & ~(size_t)255;
        return p;
    };
    int*    cnt    = (int*)alloc((size_t)C * 4);
    double* dstats = (double*)alloc((size_t)(32 + 64 + 128 + 256) * 2 * 8);
    float*  pool   = (float*)alloc((size_t)B * 256 * 4);
    int*    pcnt   = (int*)alloc((size_t)B * 4);
    size_t zeroBytes = off_;  // accumulated-into region -> zero every call
    float*  scales = (float*)alloc((size_t)(32 + 64 + 128 + 256) * 2 * 4);
    float*  y      = (float*)alloc((size_t)B * 256 * 4);
    int*    off    = (int*)alloc((size_t)C * 4);
    int*    woff   = (int*)alloc((size_t)C * 4);
    int*    bsum   = (int*)alloc((size_t)1024 * 4);
    unsigned short* w4t = (unsigned short*)alloc((size_t)256 * 128 * 2);
    void* regionA = alloc((size_t)C * 128 * 2);   // 51.2 MB: inv -> z1 -> z3
    void* regionB = alloc((size_t)C * 256 * 2);   // 102.4 MB: sorted+sfeat -> z2 -> z4
    (void)ws_size;  // total ~157 MB

    int*             inv    = (int*)regionA;              // N int (dies @gather8)
    float*           z1     = (float*)regionA;            // C x 32 f32
    __hip_bfloat16*  z3     = (__hip_bfloat16*)regionA;   // C x 128 bf16
    int*             sorted = (int*)regionB;              // N int
    float*           sfeat  = (float*)((uint8_t*)regionB + (size_t)N * 4);  // N x 5 f32
    float*           z2     = (float*)regionB;            // C x 64 f32 (after layer1)
    __hip_bfloat16*  z4     = (__hip_bfloat16*)regionB;   // C x 256 bf16 (after z2)

    double *ds1 = dstats +   0, *dq1 = dstats +  32;
    double *ds2 = dstats +  64, *dq2 = dstats + 128;
    double *ds3 = dstats + 192, *dq3 = dstats + 320;
    double *ds4 = dstats + 448, *dq4 = dstats + 704;
    float *aS1 = scales +   0, *cS1 = scales +  32;
    float *aS2 = scales +  64, *cS2 = scales + 128;
    float *aS3 = scales + 192, *cS3 = scales + 320;
    float *aS4 = scales + 448, *cS4 = scales + 704;

    const int nb  = (C + 2047) / 2048;  // scan blocks
    const int pcg = (N + 7) / 8;        // sorted positions per XCD group

    zero_kernel<<<256, 256, 0, stream>>>((float*)ws, zeroBytes / 4);
    hist_kernel<<<2048, 256, 0, stream>>>((const int4*)ccids, cnt, N / 4);
    imgcnt_kernel<<<256, 256, 0, stream>>>(imgid, pcnt, C, B);
    scan_partial<<<nb, 256, 0, stream>>>(cnt, bsum, C);
    scan_tops<<<1, 64, 0, stream>>>(bsum, nb);
    scan_final<<<nb, 256, 0, stream>>>(cnt, bsum, off, woff, C);
    scatter_inv_kernel<<<2048, 256, 0, stream>>>((const int4*)ccids, woff,
                                                 (int4*)inv, N / 4);
    gather8_kernel<<<2048, 256, 0, stream>>>(inv, item_feat, sorted, sfeat,
                                             N, pcg);
    w4conv_kernel<<<128, 256, 0, stream>>>(W4, w4t);

    layer1_kernel<<<(C + 3) / 4, 256, 0, stream>>>(sfeat, cnt, off, sorted,
                                                   W1, b1, z1, C);
    reduce_kernel<float, 32><<<512, 256, 0, stream>>>(z1, ds1, dq1, C);
    finalize_kernel<32><<<1, 32, 0, stream>>>(ds1, dq1, g1, be1, aS1, cS1, C);

    layer_kernel<float, float, 32, 64, 4, 8>
        <<<(C + 127) / 128, 256, 0, stream>>>(z1, W2, b2, aS1, cS1, z2, ds2, dq2, C);
    finalize_kernel<64><<<1, 64, 0, stream>>>(ds2, dq2, g2, be2, aS2, cS2, C);

    layer_kernel<float, __hip_bfloat16, 64, 128, 4, 8>
        <<<(C + 63) / 64, 256, 0, stream>>>(z2, W3, b3, aS2, cS2, z3, ds3, dq3, C);
    finalize_kernel<128><<<1, 128, 0, stream>>>(ds3, dq3, g3, be3, aS3, cS3, C);

    layer4_mfma<<<(C + 63) / 64, 256, 0, stream>>>(z3, w4t, b4, aS3, cS3, z4,
                                                   ds4, dq4, C);
    finalize_kernel<256><<<1, 256, 0, stream>>>(ds4, dq4, g4, be4, aS4, cS4, C);

    pool_kernel<<<512, 256, 0, stream>>>(z4, imgid, aS4, cS4, pool, C, B);
    bn5_kernel<<<1, 256, 0, stream>>>(pool, pcnt, g5, be5, y, B);

    dim3 fcg((NC + 255) / 256, B);
    fc_kernel<<<fcg, 256, 0, stream>>>(y, Wfc, bfc, out, NC);
}

// Round 7
// 1093.057 us; speedup vs baseline: 1.1993x; 1.1993x over previous
//
#include <hip/hip_runtime.h>
#include <hip/hip_bf16.h>
#include <cstdint>
#include <cstddef>

#define MAX_K 70
#define BN_EPS 1e-5f
#define KPAD 360   // 352 data + 8 pad bf16 -> row stride 720B, 2-way max bank alias

typedef __attribute__((ext_vector_type(4))) float f32x4;
typedef __attribute__((ext_vector_type(8))) short bf16x8;

// ---------------- load/store helpers (f32 or bf16 storage) ----------------
__device__ inline float loadv(const float* p, size_t i) { return p[i]; }
__device__ inline float loadv(const __hip_bfloat16* p, size_t i) {
    return __bfloat162float(p[i]);
}
__device__ inline void storev(float* p, size_t i, float v) { p[i] = v; }
__device__ inline void storev(__hip_bfloat16* p, size_t i, float v) {
    p[i] = __float2bfloat16(v);
}
__device__ inline float bf2f(unsigned short u) {
    union { unsigned int i; float f; } x; x.i = ((unsigned int)u) << 16; return x.f;
}
__device__ inline unsigned short f2bfu(float f) {
    __hip_bfloat16 h = __float2bfloat16(f);
    return *reinterpret_cast<unsigned short*>(&h);
}

// ---------------------------------------------------------------- utilities
__global__ void zero_kernel(float* __restrict__ p, size_t n) {
    size_t i = (size_t)blockIdx.x * blockDim.x + threadIdx.x;
    size_t stride = (size_t)gridDim.x * blockDim.x;
    for (; i < n; i += stride) p[i] = 0.f;
}

// ---------------- stage 1a: histogram (XCD-partitioned by ccid range) -----
__global__ __launch_bounds__(256) void hist_kernel(
    const int4* __restrict__ cc4, int* __restrict__ cnt, int n4, int cg) {
    int g  = blockIdx.x & 7;
    int k  = blockIdx.x >> 3;
    int nk = gridDim.x >> 3;
    int clo = g * cg, chi = clo + cg;
    for (int q = k * 256 + threadIdx.x; q < n4; q += nk * 256) {
        int4 v = cc4[q];
        if (v.x >= clo && v.x < chi) atomicAdd(&cnt[v.x], 1);
        if (v.y >= clo && v.y < chi) atomicAdd(&cnt[v.y], 1);
        if (v.z >= clo && v.z < chi) atomicAdd(&cnt[v.z], 1);
        if (v.w >= clo && v.w < chi) atomicAdd(&cnt[v.w], 1);
    }
}

// --------------------------------------- stage 1b: exclusive scan over cnt
__global__ __launch_bounds__(256) void scan_partial(const int* __restrict__ cnt,
                                                    int* __restrict__ bsum, int C) {
    __shared__ int sc[256];
    int b = blockIdx.x, tid = threadIdx.x;
    int base = b * 2048 + tid * 8;
    int t = 0;
    #pragma unroll
    for (int e = 0; e < 8; ++e) {
        int c = base + e;
        t += (c < C) ? cnt[c] : 0;
    }
    sc[tid] = t;
    __syncthreads();
    for (int o = 128; o > 0; o >>= 1) {
        if (tid < o) sc[tid] += sc[tid + o];
        __syncthreads();
    }
    if (tid == 0) bsum[b] = sc[0];
}

__global__ void scan_tops(int* __restrict__ bsum, int nb) {
    if (blockIdx.x == 0 && threadIdx.x == 0) {
        int run = 0;
        for (int k = 0; k < nb; ++k) { int t = bsum[k]; bsum[k] = run; run += t; }
    }
}

__global__ __launch_bounds__(256) void scan_final(const int* __restrict__ cnt,
                                                  const int* __restrict__ btop,
                                                  int* __restrict__ off,
                                                  int* __restrict__ woff, int C) {
    __shared__ int sc[256];
    int b = blockIdx.x, tid = threadIdx.x;
    int base = b * 2048 + tid * 8;
    int v[8];
    int tsum = 0;
    #pragma unroll
    for (int e = 0; e < 8; ++e) {
        int c = base + e;
        v[e] = (c < C) ? cnt[c] : 0;
        tsum += v[e];
    }
    sc[tid] = tsum;
    __syncthreads();
    for (int d = 1; d < 256; d <<= 1) {
        int t = (tid >= d) ? sc[tid - d] : 0;
        __syncthreads();
        sc[tid] += t;
        __syncthreads();
    }
    int run = btop[b] + sc[tid] - tsum;
    #pragma unroll
    for (int e = 0; e < 8; ++e) {
        int c = base + e;
        if (c < C) { off[c] = run; woff[c] = run; }
        run += v[e];
    }
}

// --------------- stage 1c: XCD-partitioned counting-sort scatter (compact)
__global__ __launch_bounds__(256) void scatter2_kernel(
    const int4* __restrict__ ccids4, int* __restrict__ woff,
    int* __restrict__ sorted, int n4, int cg) {
    int g   = blockIdx.x & 7;
    int k   = blockIdx.x >> 3;
    int nk  = gridDim.x >> 3;
    int clo = g * cg, chi = clo + cg;
    for (int q = k * 256 + threadIdx.x; q < n4; q += nk * 256) {
        int4 v = ccids4[q];
        int base = q * 4;
        #pragma unroll
        for (int e = 0; e < 4; ++e) {
            int c = (e == 0) ? v.x : (e == 1) ? v.y : (e == 2) ? v.z : v.w;
            if (c >= clo && c < chi) {
                int p = atomicAdd(&woff[c], 1);
                sorted[p] = base + e;
            }
        }
    }
}

// ----- prep: W4 -> bf16 w4t[256][128]; W1 -> bf16 w1t[32][352] (transposed)
__global__ void prep_kernel(const float* __restrict__ W4,
                            const float* __restrict__ W1,
                            unsigned short* __restrict__ w4t,
                            unsigned short* __restrict__ w1t) {
    int idx = blockIdx.x * 256 + threadIdx.x;
    if (idx < 32768) {
        int n = idx >> 7, k = idx & 127;
        w4t[idx] = f2bfu(W4[k * 256 + n]);
    } else if (idx < 32768 + 32 * 352) {
        int j = idx - 32768;
        int ch = j / 352, k = j - ch * 352;
        w1t[j] = (k < 350) ? f2bfu(W1[k * 32 + ch]) : 0;
    }
}

// --------- stage 1d+2a: rank (shfl), pack bf16 LDS tile, MFMA GEMM 350->32
// 4 waves/block, each wave owns 16 components (one 16-row MFMA A-tile)
__global__ __launch_bounds__(256) void layer1_mfma(
    const float* __restrict__ feat, const int* __restrict__ cnt,
    const int* __restrict__ off, const int* __restrict__ sorted,
    const unsigned short* __restrict__ w1t, const float* __restrict__ b1,
    float* __restrict__ z1, int C) {
    __shared__ unsigned short xtile[4][16][KPAD];  // 46 KB
    int tid  = threadIdx.x;
    int w    = tid >> 6;
    int lane = tid & 63;
    int cbase = blockIdx.x * 64 + w * 16;

    for (int sub = 0; sub < 16; ++sub) {
        int comp = cbase + sub;
        int flen = 0, base = 0;
        if (comp < C) { flen = cnt[comp]; base = off[comp]; }
        // zero this comp's row (pad + missing ranks)
        unsigned int* xr = (unsigned int*)&xtile[w][sub][0];
        for (int t = lane; t < KPAD / 2; t += 64) xr[t] = 0u;
        if (flen <= 64) {
            // register rank: lane e holds member e's original index
            int my = (lane < flen) ? sorted[base + lane] : 0;
            int r = 0;
            for (int j = 0; j < flen; ++j) {
                int oth = __shfl(my, j);
                r += (oth < my) ? 1 : 0;
            }
            if (lane < flen) {  // flen<=64<70 -> r<MAX_K guaranteed
                size_t fb = (size_t)my * 5;
                float f0 = feat[fb + 0], f1 = feat[fb + 1], f2 = feat[fb + 2];
                float f3 = feat[fb + 3], f4 = feat[fb + 4];
                unsigned short* xp = &xtile[w][sub][r * 5];
                xp[0] = f2bfu(f0); xp[1] = f2bfu(f1); xp[2] = f2bfu(f2);
                xp[3] = f2bfu(f3); xp[4] = f2bfu(f4);
            }
        } else {
            // rare fallback: rank via global sorted
            for (int e = lane; e < flen; e += 64) {
                int my = sorted[base + e];
                int r = 0;
                for (int j = 0; j < flen; ++j)
                    r += (sorted[base + j] < my) ? 1 : 0;
                if (r < MAX_K) {
                    size_t fb = (size_t)my * 5;
                    unsigned short* xp = &xtile[w][sub][r * 5];
                    xp[0] = f2bfu(feat[fb + 0]); xp[1] = f2bfu(feat[fb + 1]);
                    xp[2] = f2bfu(feat[fb + 2]); xp[3] = f2bfu(feat[fb + 3]);
                    xp[4] = f2bfu(feat[fb + 4]);
                }
            }
        }
    }
    __syncthreads();  // xtile writes -> cross-lane MFMA fragment reads

    int l15 = lane & 15, l4 = lane >> 4;
    f32x4 acc0 = {0.f, 0.f, 0.f, 0.f};
    f32x4 acc1 = {0.f, 0.f, 0.f, 0.f};
    const unsigned short* xbase = &xtile[w][l15][0];
    #pragma unroll
    for (int ks = 0; ks < 11; ++ks) {
        int k0 = ks * 32 + l4 * 8;
        bf16x8 a  = *(const bf16x8*)&xbase[k0];
        bf16x8 b0 = *(const bf16x8*)&w1t[(size_t)l15 * 352 + k0];
        bf16x8 bv = *(const bf16x8*)&w1t[(size_t)(16 + l15) * 352 + k0];
        acc0 = __builtin_amdgcn_mfma_f32_16x16x32_bf16(a, b0, acc0, 0, 0, 0);
        acc1 = __builtin_amdgcn_mfma_f32_16x16x32_bf16(a, bv, acc1, 0, 0, 0);
    }
    float bias0 = b1[l15];
    float bias1 = b1[16 + l15];
    #pragma unroll
    for (int r = 0; r < 4; ++r) {
        int comp = cbase + l4 * 4 + r;
        if (comp < C) {
            z1[(size_t)comp * 32 + l15]      = acc0[r] + bias0;
            z1[(size_t)comp * 32 + 16 + l15] = acc1[r] + bias1;
        }
    }
}

// --------------------------------------- per-channel sum / sumsq reduction
template <typename T, int FO>
__global__ __launch_bounds__(256) void reduce_kernel(
    const T* __restrict__ z, double* __restrict__ dsum,
    double* __restrict__ dsq, int C) {
    size_t n = (size_t)C * FO;
    size_t i = (size_t)blockIdx.x * 256 + threadIdx.x;
    size_t stride = (size_t)gridDim.x * 256;
    double s = 0.0, s2 = 0.0;
    for (; i < n; i += stride) {
        double v = (double)loadv(z, i);
        s += v; s2 += v * v;
    }
    __shared__ double ss[256], ssq[256];
    int tid = threadIdx.x;
    ss[tid] = s; ssq[tid] = s2;
    __syncthreads();
    for (int off = (256 / FO) >> 1; off > 0; off >>= 1) {
        if (tid < off * FO) {
            ss[tid]  += ss[tid + off * FO];
            ssq[tid] += ssq[tid + off * FO];
        }
        __syncthreads();
    }
    if (tid < FO) {
        unsafeAtomicAdd(&dsum[tid], ss[tid]);
        unsafeAtomicAdd(&dsq[tid],  ssq[tid]);
    }
}

// ------------------------------- fold BN stats into per-channel scale/shift
template <int FO>
__global__ void finalize_kernel(const double* __restrict__ dsum,
                                const double* __restrict__ dsq,
                                const float* __restrict__ g,
                                const float* __restrict__ be,
                                float* __restrict__ aS, float* __restrict__ cS,
                                int C) {
    int ch = threadIdx.x;
    if (ch < FO) {
        double m = dsum[ch] / (double)C;
        double v = dsq[ch] / (double)C - m * m;
        float rs = rsqrtf((float)v + BN_EPS);
        float a = g[ch] * rs;
        aS[ch] = a;
        cS[ch] = be[ch] - (float)m * a;
    }
}

// ---- generic layer: zout = relu(aS*zin+cS) @ W + b, with fused BN stats ----
template <typename TI, typename TO, int FI, int FO, int CT, int RT>
__global__ __launch_bounds__(256) void layer_kernel(
    const TI* __restrict__ zin, const float* __restrict__ W,
    const float* __restrict__ bias, const float* __restrict__ aS,
    const float* __restrict__ cS, TO* __restrict__ zout,
    double* __restrict__ dsum, double* __restrict__ dsq, int C) {
    constexpr int CHG  = FO / CT;
    constexpr int NSUB = 256 / CHG;
    constexpr int R    = NSUB * RT;
    __shared__ float h[R][FI + 1];
    __shared__ float sps[NSUB * FO];
    __shared__ float spq[NSUB * FO];
    int tid = threadIdx.x;
    int c0 = blockIdx.x * R;
    for (int t = tid; t < R * FI; t += 256) {
        int r = t / FI, k = t % FI;
        int c = c0 + r;
        float v = (c < C) ? loadv(zin, (size_t)c * FI + k) : 0.f;
        h[r][k] = fmaxf(fmaf(aS[k], v, cS[k]), 0.f);
    }
    __syncthreads();
    int cg  = tid % CHG;
    int sub = tid / CHG;
    int chbase = cg * CT;
    float acc[RT][CT];
    #pragma unroll
    for (int i = 0; i < RT; ++i)
        #pragma unroll
        for (int j = 0; j < CT; ++j) acc[i][j] = 0.f;
    for (int k = 0; k < FI; ++k) {
        float wv[CT];
        #pragma unroll
        for (int j4 = 0; j4 < CT; j4 += 4) {
            const float4 wq = *reinterpret_cast<const float4*>(
                &W[(size_t)k * FO + chbase + j4]);
            wv[j4 + 0] = wq.x; wv[j4 + 1] = wq.y;
            wv[j4 + 2] = wq.z; wv[j4 + 3] = wq.w;
        }
        #pragma unroll
        for (int i = 0; i < RT; ++i) {
            float hv = h[sub * RT + i][k];
            #pragma unroll
            for (int j = 0; j < CT; ++j) acc[i][j] = fmaf(hv, wv[j], acc[i][j]);
        }
    }
    float ps[CT], pq[CT];
    #pragma unroll
    for (int j = 0; j < CT; ++j) { ps[j] = 0.f; pq[j] = 0.f; }
    #pragma unroll
    for (int i = 0; i < RT; ++i) {
        int c = c0 + sub * RT + i;
        if (c < C) {
            #pragma unroll
            for (int j = 0; j < CT; ++j) {
                float z = acc[i][j] + bias[chbase + j];
                storev(zout, (size_t)c * FO + chbase + j, z);
                ps[j] += z;
                pq[j] += z * z;
            }
        }
    }
    #pragma unroll
    for (int j = 0; j < CT; ++j) {
        sps[sub * FO + chbase + j] = ps[j];
        spq[sub * FO + chbase + j] = pq[j];
    }
    __syncthreads();
    if (tid < FO) {
        float s = 0.f, q = 0.f;
        #pragma unroll
        for (int s2 = 0; s2 < NSUB; ++s2) {
            s += sps[s2 * FO + tid];
            q += spq[s2 * FO + tid];
        }
        unsafeAtomicAdd(&dsum[tid], (double)s);
        unsafeAtomicAdd(&dsq[tid],  (double)q);
    }
}

// ------------- layer 4 via MFMA: z4 = relu(bn3(z3)) @ W4 + b4, fused stats
__global__ __launch_bounds__(256) void layer4_mfma(
    const __hip_bfloat16* __restrict__ z3, const unsigned short* __restrict__ w4t,
    const float* __restrict__ b4, const float* __restrict__ aS,
    const float* __restrict__ cS, __hip_bfloat16* __restrict__ z4,
    double* __restrict__ dsum, double* __restrict__ dsq, int C) {
    __shared__ float sps[2][256];
    __shared__ float spq[2][256];
    int tid = threadIdx.x, wid = tid >> 6, lane = tid & 63;
    int wm = wid >> 1, wn = wid & 1;
    int c0 = blockIdx.x * 64;
    int l15 = lane & 15, l4 = lane >> 4;
    const unsigned short* z3u = (const unsigned short*)z3;

    f32x4 acc[2][8];
    #pragma unroll
    for (int mi = 0; mi < 2; ++mi)
        #pragma unroll
        for (int ni = 0; ni < 8; ++ni) acc[mi][ni] = (f32x4){0.f, 0.f, 0.f, 0.f};

    int rowA0 = c0 + wm * 32 + l15;
    #pragma unroll
    for (int ks = 0; ks < 4; ++ks) {
        int k0 = ks * 32 + l4 * 8;
        float sc[8], cc[8];
        {
            float4 a0 = *(const float4*)&aS[k0];
            float4 a1 = *(const float4*)&aS[k0 + 4];
            float4 c0v = *(const float4*)&cS[k0];
            float4 c1v = *(const float4*)&cS[k0 + 4];
            sc[0] = a0.x; sc[1] = a0.y; sc[2] = a0.z; sc[3] = a0.w;
            sc[4] = a1.x; sc[5] = a1.y; sc[6] = a1.z; sc[7] = a1.w;
            cc[0] = c0v.x; cc[1] = c0v.y; cc[2] = c0v.z; cc[3] = c0v.w;
            cc[4] = c1v.x; cc[5] = c1v.y; cc[6] = c1v.z; cc[7] = c1v.w;
        }
        bf16x8 afrag[2];
        #pragma unroll
        for (int mi = 0; mi < 2; ++mi) {
            int r = rowA0 + mi * 16;
            int rc = (r < C) ? r : (C - 1);
            bf16x8 raw = *(const bf16x8*)&z3u[(size_t)rc * 128 + k0];
            bf16x8 af;
            #pragma unroll
            for (int j = 0; j < 8; ++j) {
                float v = bf2f((unsigned short)raw[j]);
                float hx = fmaxf(fmaf(sc[j], v, cc[j]), 0.f);
                af[j] = (short)f2bfu((r < C) ? hx : 0.f);
            }
            afrag[mi] = af;
        }
        bf16x8 bfrag[8];
        #pragma unroll
        for (int ni = 0; ni < 8; ++ni) {
            int n = wn * 128 + ni * 16 + l15;
            bfrag[ni] = *(const bf16x8*)&w4t[(size_t)n * 128 + k0];
        }
        #pragma unroll
        for (int mi = 0; mi < 2; ++mi)
            #pragma unroll
            for (int ni = 0; ni < 8; ++ni)
                acc[mi][ni] = __builtin_amdgcn_mfma_f32_16x16x32_bf16(
                    afrag[mi], bfrag[ni], acc[mi][ni], 0, 0, 0);
    }
    unsigned short* z4u = (unsigned short*)z4;
    #pragma unroll
    for (int ni = 0; ni < 8; ++ni) {
        int col = wn * 128 + ni * 16 + l15;
        float bv = b4[col];
        float s = 0.f, q = 0.f;
        #pragma unroll
        for (int mi = 0; mi < 2; ++mi) {
            #pragma unroll
            for (int r = 0; r < 4; ++r) {
                int row = c0 + wm * 32 + mi * 16 + l4 * 4 + r;
                float z = acc[mi][ni][r] + bv;
                if (row < C) {
                    z4u[(size_t)row * 256 + col] = f2bfu(z);
                    s += z;
                    q += z * z;
                }
            }
        }
        s += __shfl_xor(s, 16); s += __shfl_xor(s, 32);
        q += __shfl_xor(q, 16); q += __shfl_xor(q, 32);
        if (lane < 16) { sps[wm][col] = s; spq[wm][col] = q; }
    }
    __syncthreads();
    if (tid < 256) {
        float s = sps[0][tid] + sps[1][tid];
        float q = spq[0][tid] + spq[1][tid];
        unsafeAtomicAdd(&dsum[tid], (double)s);
        unsafeAtomicAdd(&dsq[tid],  (double)q);
    }
}

// ----------------------------------------------- per-image component counts
__global__ void imgcnt_kernel(const int* __restrict__ imgid,
                              int* __restrict__ pcnt, int C, int B) {
    __shared__ int scnt[64];
    int tid = threadIdx.x;
    if (tid < B) scnt[tid] = 0;
    __syncthreads();
    for (int i = blockIdx.x * 256 + tid; i < C; i += gridDim.x * 256)
        atomicAdd(&scnt[imgid[i]], 1);
    __syncthreads();
    if (tid < B) atomicAdd(&pcnt[tid], scnt[tid]);
}

// ------------- segment-sum of relu(bn4(z4)) into pool[B,256] (LDS accum)
__global__ __launch_bounds__(256) void pool_kernel(
    const __hip_bfloat16* __restrict__ z4, const int* __restrict__ imgid,
    const float* __restrict__ aS, const float* __restrict__ cS,
    float* __restrict__ pool, int C, int B) {
    __shared__ float spool[64 * 256];
    int tid = threadIdx.x;
    int nb = B * 256;
    for (int t = tid; t < nb; t += 256) spool[t] = 0.f;
    __syncthreads();
    float a = aS[tid], cc = cS[tid];
    int per  = (C + gridDim.x - 1) / gridDim.x;
    int cbeg = blockIdx.x * per;
    int cend = min(cbeg + per, C);
    for (int c = cbeg; c < cend; ++c) {
        int img = imgid[c];
        float v = loadv(z4, (size_t)c * 256 + tid);
        float hv = fmaxf(fmaf(a, v, cc), 0.f);
        spool[img * 256 + tid] += hv;
    }
    __syncthreads();
    int start = ((int)blockIdx.x * 2048) % nb;
    for (int t0 = 0; t0 < nb; t0 += 256) {
        int t = (start + t0 + tid) % nb;
        unsafeAtomicAdd(&pool[t], spool[t]);
    }
}

// ------------------------------ mean over comps, BN over the 64 image rows
__global__ void bn5_kernel(const float* __restrict__ pool,
                           const int* __restrict__ pcnt,
                           const float* __restrict__ g5,
                           const float* __restrict__ be5,
                           float* __restrict__ y, int B) {
    int ch = threadIdx.x;
    double s = 0.0, s2 = 0.0;
    for (int b = 0; b < B; ++b) {
        float c = (float)pcnt[b]; if (c < 1.f) c = 1.f;
        float v = pool[b * 256 + ch] / c;
        s += (double)v; s2 += (double)v * (double)v;
    }
    double m = s / (double)B;
    double var = s2 / (double)B - m * m;
    float rs = rsqrtf((float)var + BN_EPS);
    float a = g5[ch] * rs;
    float cc = be5[ch] - (float)m * a;
    for (int b = 0; b < B; ++b) {
        float c = (float)pcnt[b]; if (c < 1.f) c = 1.f;
        float v = pool[b * 256 + ch] / c;
        y[b * 256 + ch] = fmaf(a, v, cc);
    }
}

// ------------------------------------------------------- final FC + ReLU
__global__ __launch_bounds__(256) void fc_kernel(
    const float* __restrict__ y, const float* __restrict__ Wfc,
    const float* __restrict__ bfc, float* __restrict__ out, int NC) {
    int b = blockIdx.y;
    int ch = blockIdx.x * 256 + threadIdx.x;
    __shared__ float sy[256];
    sy[threadIdx.x] = y[b * 256 + threadIdx.x];
    __syncthreads();
    if (ch < NC) {
        float acc = bfc[ch];
        for (int k = 0; k < 256; ++k)
            acc = fmaf(sy[k], Wfc[(size_t)k * NC + ch], acc);
        out[(size_t)b * NC + ch] = fmaxf(acc, 0.f);
    }
}

// ---------------------------------------------------------------- launcher
extern "C" void kernel_launch(void* const* d_in, const int* in_sizes, int n_in,
                              void* d_out, int out_size, void* d_ws,
                              size_t ws_size, hipStream_t stream) {
    const float* item_feat = (const float*)d_in[0];
    const int*   ccids     = (const int*)d_in[1];
    const int*   imgid     = (const int*)d_in[2];
    const float* W1  = (const float*)d_in[3];
    const float* b1  = (const float*)d_in[4];
    const float* g1  = (const float*)d_in[5];
    const float* be1 = (const float*)d_in[6];
    const float* W2  = (const float*)d_in[7];
    const float* b2  = (const float*)d_in[8];
    const float* g2  = (const float*)d_in[9];
    const float* be2 = (const float*)d_in[10];
    const float* W3  = (const float*)d_in[11];
    const float* b3  = (const float*)d_in[12];
    const float* g3  = (const float*)d_in[13];
    const float* be3 = (const float*)d_in[14];
    const float* W4  = (const float*)d_in[15];
    const float* b4  = (const float*)d_in[16];
    const float* g4  = (const float*)d_in[17];
    const float* be4 = (const float*)d_in[18];
    const float* g5  = (const float*)d_in[19];
    const float* be5 = (const float*)d_in[20];
    const float* Wfc = (const float*)d_in[21];
    const float* bfc = (const float*)d_in[22];
    float* out = (float*)d_out;

    const int N  = in_sizes[1];        // 4,000,000 items
    const int C  = in_sizes[2];        // 200,000 components
    const int NC = in_sizes[22];       // 1000 classes
    const int B  = out_size / NC;      // 64 images

    // ---- workspace layout: explicit liveness-based aliasing ----
    uint8_t* ws = (uint8_t*)d_ws;
    size_t off_ = 0;
    auto alloc = [&](size_t bytes) -> void* {
        void* p = (void*)(ws + off_);
        off_ += (bytes + 255) & ~(size_t)255;
        return p;
    };
    int*    cnt    = (int*)alloc((size_t)C * 4);
    double* dstats = (double*)alloc((size_t)(32 + 64 + 128 + 256) * 2 * 8);
    float*  pool   = (float*)alloc((size_t)B * 256 * 4);
    int*    pcnt   = (int*)alloc((size_t)B * 4);
    size_t zeroBytes = off_;  // accumulated-into region -> zero every call
    float*  scales = (float*)alloc((size_t)(32 + 64 + 128 + 256) * 2 * 4);
    float*  y      = (float*)alloc((size_t)B * 256 * 4);
    int*    off    = (int*)alloc((size_t)C * 4);
    int*    woff   = (int*)alloc((size_t)C * 4);
    int*    bsum   = (int*)alloc((size_t)1024 * 4);
    unsigned short* w4t = (unsigned short*)alloc((size_t)256 * 128 * 2);
    unsigned short* w1t = (unsigned short*)alloc((size_t)32 * 352 * 2);
    void* regionA = alloc((size_t)C * 128 * 2);   // 51.2 MB: z1 f32 -> z3 bf16
    void* regionB = alloc((size_t)C * 256 * 2);   // 102.4 MB: sorted -> z2 -> z4
    (void)ws_size;  // total ~157 MB

    float*           z1     = (float*)regionA;            // C x 32 f32
    __hip_bfloat16*  z3     = (__hip_bfloat16*)regionA;   // C x 128 bf16
    int*             sorted = (int*)regionB;              // N int (dies @L1)
    float*           z2     = (float*)regionB;            // C x 64 f32 (dies @L3)
    __hip_bfloat16*  z4     = (__hip_bfloat16*)regionB;   // C x 256 bf16

    double *ds1 = dstats +   0, *dq1 = dstats +  32;
    double *ds2 = dstats +  64, *dq2 = dstats + 128;
    double *ds3 = dstats + 192, *dq3 = dstats + 320;
    double *ds4 = dstats + 448, *dq4 = dstats + 704;
    float *aS1 = scales +   0, *cS1 = scales +  32;
    float *aS2 = scales +  64, *cS2 = scales + 128;
    float *aS3 = scales + 192, *cS3 = scales + 320;
    float *aS4 = scales + 448, *cS4 = scales + 704;

    const int nb = (C + 2047) / 2048;  // scan blocks
    const int cg = (C + 7) / 8;        // comps per XCD group

    zero_kernel<<<256, 256, 0, stream>>>((float*)ws, zeroBytes / 4);
    hist_kernel<<<2048, 256, 0, stream>>>((const int4*)ccids, cnt, N / 4, cg);
    imgcnt_kernel<<<256, 256, 0, stream>>>(imgid, pcnt, C, B);
    scan_partial<<<nb, 256, 0, stream>>>(cnt, bsum, C);
    scan_tops<<<1, 64, 0, stream>>>(bsum, nb);
    scan_final<<<nb, 256, 0, stream>>>(cnt, bsum, off, woff, C);
    scatter2_kernel<<<2048, 256, 0, stream>>>((const int4*)ccids, woff, sorted,
                                              N / 4, cg);
    prep_kernel<<<172, 256, 0, stream>>>(W4, W1, w4t, w1t);

    layer1_mfma<<<(C + 63) / 64, 256, 0, stream>>>(item_feat, cnt, off, sorted,
                                                   w1t, b1, z1, C);
    reduce_kernel<float, 32><<<512, 256, 0, stream>>>(z1, ds1, dq1, C);
    finalize_kernel<32><<<1, 32, 0, stream>>>(ds1, dq1, g1, be1, aS1, cS1, C);

    layer_kernel<float, float, 32, 64, 4, 8>
        <<<(C + 127) / 128, 256, 0, stream>>>(z1, W2, b2, aS1, cS1, z2, ds2, dq2, C);
    finalize_kernel<64><<<1, 64, 0, stream>>>(ds2, dq2, g2, be2, aS2, cS2, C);

    layer_kernel<float, __hip_bfloat16, 64, 128, 4, 8>
        <<<(C + 63) / 64, 256, 0, stream>>>(z2, W3, b3, aS2, cS2, z3, ds3, dq3, C);
    finalize_kernel<128><<<1, 128, 0, stream>>>(ds3, dq3, g3, be3, aS3, cS3, C);

    layer4_mfma<<<(C + 63) / 64, 256, 0, stream>>>(z3, w4t, b4, aS3, cS3, z4,
                                                   ds4, dq4, C);
    finalize_kernel<256><<<1, 256, 0, stream>>>(ds4, dq4, g4, be4, aS4, cS4, C);

    pool_kernel<<<512, 256, 0, stream>>>(z4, imgid, aS4, cS4, pool, C, B);
    bn5_kernel<<<1, 256, 0, stream>>>(pool, pcnt, g5, be5, y, B);

    dim3 fcg((NC + 255) / 256, B);
    fc_kernel<<<fcg, 256, 0, stream>>>(y, Wfc, bfc, out, NC);
}